// Round 1
// baseline (3425.513 us; speedup 1.0000x reference)
//
#include <hip/hip_runtime.h>
#include <math.h>

#define T_STEPS 2048
#define HID     128
#define G4      512   // 4*H

typedef _Float16 half8 __attribute__((ext_vector_type(8)));
typedef float    f32x4 __attribute__((ext_vector_type(4)));

__device__ __forceinline__ float fast_sig(float x) {
    return __fdividef(1.0f, 1.0f + __expf(-x));
}
__device__ __forceinline__ float fast_tanh(float x) {
    return fmaf(2.0f, __fdividef(1.0f, 1.0f + __expf(-2.0f * x)), -1.0f);
}

// ---------------------------------------------------------------------------
// MFMA LSTM recurrence, single live batch element (b = 127).
//
// ROUND 5 RESTRUCTURE (theory: old version was 2090 cy/step with ~460 cy of
// real work; the rest was 2 barriers/step + gact LDS round-trip + serial
// 128-thread tail + vmcnt(0) drains of the hout store and pre prefetch at
// each barrier):
//
//  * UNIT-INTERLEAVED gate ownership: wave w, r-tile r (r = 2g+b) covers
//    gates gate_base(w,r) = 128*(r>>1) + w*32 + 16*(r&1). Since B (h) is
//    broadcast, all 16 MFMA columns hold identical acc, so lane (q, c<8)
//    with b=c>>2, reg=c&3 ALREADY holds all four gate pre-activations of
//    hidden unit u = w*32 + 16b + 4q + reg in acc[{b,2+b,4+b,6+b}][reg].
//    -> i/f/g/o gathered by a static unrolled select, c/h updated fully
//    in-lane. No gact buffer, no barrier B, no serial tail.
//  * ONE barrier per step + double-buffered h16[2][128]; the end-of-step
//    barrier separates this step's h16 reads from next step's writes.
//  * hout store deferred one step and issued at step START, so its vmcnt
//    drain at the barrier is covered by MFMA+activation work.
//  * L0 pre-activation = bsum4 + w4 * x_s[t] from 8 resident regs + LDS x
//    table (no steady-state global loads). L1 pre-activation = 4 scalar
//    loads of G[t+1] per act-lane, prefetched one step ahead.
//
// Occupancy trick retained from rounds 2-4: the RA's VGPR budget follows
// LDS-bounded occupancy only; 56 KB dummy pad -> 2 WG/CU -> 2 waves/EU ->
// 256-reg budget; demand ~200 regs.
// ---------------------------------------------------------------------------
template<bool IS_L0>
__global__ __launch_bounds__(256)
void lstm_rec_mfma(const float* __restrict__ Whh,   // (512,128) row-major
                   const float* __restrict__ xin,   // L0: x (T,128) ; L1: G (T,512)
                   const float* __restrict__ wih0,  // L0 only (512,)
                   const float* __restrict__ bih,   // L0 only
                   const float* __restrict__ bhh,   // L0 only
                   float* __restrict__ hout)        // (T,128)
{
    const int tid  = threadIdx.x;
    const int wave = tid >> 6;         // 0..3
    const int lane = tid & 63;
    const int quad = lane >> 4;
    const int col  = lane & 15;

    const bool act_lane = (col < 8);
    const int  b_  = (col >> 2) & 1;     // which 16-block (valid for col<8)
    const int  rg  = col & 3;            // acc register index
    const int  u   = wave * 32 + 16 * b_ + quad * 4 + rg;  // hidden unit (col<8)

    __shared__ __align__(16) _Float16 h16[2][HID];   // double-buffered h (f16)
    __shared__ float x_s[T_STEPS];                   // L0: x[t,127] table (8 KB)
    __shared__ char occupancy_pad[56 * 1024];        // caps occupancy at 2 WG/CU
    ((volatile char*)occupancy_pad)[tid] = 0;        // keep the pad alive

    // A fragments, unit-interleaved:
    // afrag[r][kt] = Whh[gate_base(w,r) + col][kt*32 + quad*8 + j]
    half8 afrag[8][4];
    #pragma unroll
    for (int r = 0; r < 8; ++r) {
        const int gb = 128 * (r >> 1) + wave * 32 + 16 * (r & 1);
        const float* row = Whh + (size_t)(gb + col) * HID;
        #pragma unroll
        for (int kt = 0; kt < 4; ++kt) {
            const float4* p = reinterpret_cast<const float4*>(row + kt * 32 + quad * 8);
            float4 lo = p[0], hi = p[1];
            half8 h;
            h[0] = (_Float16)lo.x; h[1] = (_Float16)lo.y;
            h[2] = (_Float16)lo.z; h[3] = (_Float16)lo.w;
            h[4] = (_Float16)hi.x; h[5] = (_Float16)hi.y;
            h[6] = (_Float16)hi.z; h[7] = (_Float16)hi.w;
            afrag[r][kt] = h;
        }
    }

    // L0: per-lane pre-activation constants for THIS lane's unit (8 regs):
    // bsum4[g] = bih[128g+u]+bhh[128g+u], w4[g] = wih0[128g+u]
    f32x4 bsum4 = {0,0,0,0}, w4 = {0,0,0,0};
    if (IS_L0) {
        if (act_lane) {
            #pragma unroll
            for (int g = 0; g < 4; ++g) {
                bsum4[g] = bih[128 * g + u] + bhh[128 * g + u];
                w4[g]    = wih0[128 * g + u];
            }
        }
        // x table: x[t,127,0] at stride 128
        for (int i = tid; i < T_STEPS; i += 256)
            x_s[i] = xin[(size_t)i * HID + HID - 1];
    }

    // pin loop-invariants (defeat remat)
    #pragma unroll
    for (int r = 0; r < 8; ++r)
        #pragma unroll
        for (int kt = 0; kt < 4; ++kt) asm volatile("" : "+v"(afrag[r][kt]));
    if (IS_L0) asm volatile("" : "+v"(bsum4), "+v"(w4));

    // L1: pre-activation pipeline, 4 scalar gate values per act-lane
    f32x4 pre_cur = {0,0,0,0}, pre_nxt = {0,0,0,0};
    if (!IS_L0) {
        if (act_lane) {
            #pragma unroll
            for (int g = 0; g < 4; ++g)
                pre_cur[g] = xin[128 * g + u];     // G[0][gate]
        }
    }

    if (tid < HID) h16[0][tid] = (_Float16)0.0f;
    __syncthreads();

    float c_reg  = 0.0f;
    float h_prev = 0.0f;

    for (int t = 0; t < T_STEPS; ++t) {
        // B fragments: broadcast read of h[t-1] from slot t&1
        half8 bfrag[4];
        #pragma unroll
        for (int kt = 0; kt < 4; ++kt)
            bfrag[kt] = *reinterpret_cast<const half8*>(&h16[t & 1][kt * 32 + quad * 8]);

        // deferred global store of h[t-1]: issued early, drained (covered)
        // at the end-of-step barrier
        if (t > 0 && act_lane)
            hout[(size_t)(t - 1) * HID + u] = h_prev;

        // L1: prefetch next step's 4 pre-activation gates (L3-resident G)
        const int tn = (t + 1 < T_STEPS) ? t + 1 : t;
        if (!IS_L0) {
            if (act_lane) {
                #pragma unroll
                for (int g = 0; g < 4; ++g)
                    pre_nxt[g] = xin[(size_t)tn * G4 + 128 * g + u];
            }
            asm volatile("" : "+v"(pre_nxt));   // force issue here
        }

        // D = Whh_tile @ h   (32 MFMA, 8 independent accumulator chains)
        f32x4 acc[8] = {};
        #pragma unroll
        for (int kt = 0; kt < 4; ++kt) {
            #pragma unroll
            for (int r = 0; r < 8; ++r)
                acc[r] = __builtin_amdgcn_mfma_f32_16x16x32_f16(
                             afrag[r][kt], bfrag[kt], acc[r], 0, 0, 0);
        }

        // in-lane gather of this unit's i/f/g/o (static unrolled select,
        // no dynamic register indexing -> no scratch)
        float gi = 0.f, gf = 0.f, gg = 0.f, go = 0.f;
        #pragma unroll
        for (int cs = 0; cs < 8; ++cs) {
            if (col == cs) {
                const int bb = cs >> 2, rr = cs & 3;
                gi = acc[bb + 0][rr];
                gf = acc[bb + 2][rr];
                gg = acc[bb + 4][rr];
                go = acc[bb + 6][rr];
            }
        }

        // add pre-activation (bias + input-path contribution)
        f32x4 pre;
        if (IS_L0) {
            const float xv = x_s[t];
            pre = bsum4 + w4 * xv;
        } else {
            pre = pre_cur;
        }
        gi += pre[0]; gf += pre[1]; gg += pre[2]; go += pre[3];

        // activations + in-lane c/h update (c-state lives in one VGPR)
        const float ai = fast_sig(gi);
        const float af = fast_sig(gf);
        const float ag = fast_tanh(gg);
        const float ao = fast_sig(go);
        c_reg = fmaf(af, c_reg, ai * ag);
        const float h = ao * fast_tanh(c_reg);

        if (act_lane)
            h16[(t + 1) & 1][u] = (_Float16)h;
        h_prev = h;
        if (!IS_L0) pre_cur = pre_nxt;

        __syncthreads();
    }
    if (act_lane)
        hout[(size_t)(T_STEPS - 1) * HID + u] = h_prev;
}

// ---------------------------------------------------------------------------
// C[m,n] = sum_k A[m,k] * W[n,k] + b1[n] (+ b2[n])    K = 128 fixed
// ---------------------------------------------------------------------------
#define BM 64
#define BN 64
__global__ __launch_bounds__(256)
void gemm_bias_kernel(const float* __restrict__ A,   // (M,128)
                      const float* __restrict__ W,   // (N,128)
                      const float* __restrict__ b1,
                      const float* __restrict__ b2,  // may be null
                      float* __restrict__ C,         // (M,N)
                      int M, int N)
{
    __shared__ float Al[128][BM + 4];
    __shared__ float Wl[128][BN + 4];
    const int tid    = threadIdx.x;
    const int m_base = blockIdx.x * BM;
    const int n_base = blockIdx.y * BN;

    {
        const int r  = tid >> 2;          // 0..63
        const int kq = (tid & 3) * 32;    // 0,32,64,96
        const float4* srcA = reinterpret_cast<const float4*>(A + (size_t)(m_base + r) * 128 + kq);
        #pragma unroll
        for (int i = 0; i < 8; ++i) {
            float4 v = srcA[i];
            int k = kq + 4 * i;
            Al[k + 0][r] = v.x; Al[k + 1][r] = v.y; Al[k + 2][r] = v.z; Al[k + 3][r] = v.w;
        }
        const float4* srcW = reinterpret_cast<const float4*>(W + (size_t)(n_base + r) * 128 + kq);
        #pragma unroll
        for (int i = 0; i < 8; ++i) {
            float4 v = srcW[i];
            int k = kq + 4 * i;
            Wl[k + 0][r] = v.x; Wl[k + 1][r] = v.y; Wl[k + 2][r] = v.z; Wl[k + 3][r] = v.w;
        }
    }
    __syncthreads();

    const int tm = (tid & 15) * 4;
    const int tn = (tid >> 4) * 4;
    float acc[4][4] = {};
    #pragma unroll 8
    for (int k = 0; k < 128; ++k) {
        float4 av = *reinterpret_cast<const float4*>(&Al[k][tm]);
        float4 wv = *reinterpret_cast<const float4*>(&Wl[k][tn]);
        acc[0][0] = fmaf(av.x, wv.x, acc[0][0]);
        acc[0][1] = fmaf(av.x, wv.y, acc[0][1]);
        acc[0][2] = fmaf(av.x, wv.z, acc[0][2]);
        acc[0][3] = fmaf(av.x, wv.w, acc[0][3]);
        acc[1][0] = fmaf(av.y, wv.x, acc[1][0]);
        acc[1][1] = fmaf(av.y, wv.y, acc[1][1]);
        acc[1][2] = fmaf(av.y, wv.z, acc[1][2]);
        acc[1][3] = fmaf(av.y, wv.w, acc[1][3]);
        acc[2][0] = fmaf(av.z, wv.x, acc[2][0]);
        acc[2][1] = fmaf(av.z, wv.y, acc[2][1]);
        acc[2][2] = fmaf(av.z, wv.z, acc[2][2]);
        acc[2][3] = fmaf(av.z, wv.w, acc[2][3]);
        acc[3][0] = fmaf(av.w, wv.x, acc[3][0]);
        acc[3][1] = fmaf(av.w, wv.y, acc[3][1]);
        acc[3][2] = fmaf(av.w, wv.z, acc[3][2]);
        acc[3][3] = fmaf(av.w, wv.w, acc[3][3]);
    }

    float bias[4];
    #pragma unroll
    for (int i = 0; i < 4; ++i) {
        int n = n_base + tn + i;
        bias[i] = b1[n] + (b2 ? b2[n] : 0.0f);
    }
    #pragma unroll
    for (int mi = 0; mi < 4; ++mi) {
        float4 o;
        o.x = acc[mi][0] + bias[0];
        o.y = acc[mi][1] + bias[1];
        o.z = acc[mi][2] + bias[2];
        o.w = acc[mi][3] + bias[3];
        *reinterpret_cast<float4*>(C + (size_t)(m_base + tm + mi) * N + n_base + tn) = o;
    }
}

// ---------------------------------------------------------------------------
__global__ __launch_bounds__(512)
void bn_stats_kernel(const float* __restrict__ Z,       // (T,128)
                     const float* __restrict__ gamma,
                     const float* __restrict__ beta,
                     float* __restrict__ scale,
                     float* __restrict__ shift)
{
    const int tid = threadIdx.x;
    const int col = tid & 127;
    const int seg = tid >> 7;     // 0..3
    float s = 0.f, sq = 0.f;
    for (int t = seg * 512; t < (seg + 1) * 512; ++t) {
        float v = Z[(size_t)t * 128 + col];
        s += v;
        sq = fmaf(v, v, sq);
    }
    __shared__ float ps[4][128], pq[4][128];
    ps[seg][col] = s;
    pq[seg][col] = sq;
    __syncthreads();
    if (tid < 128) {
        float sum = ps[0][tid] + ps[1][tid] + ps[2][tid] + ps[3][tid];
        float sqq = pq[0][tid] + pq[1][tid] + pq[2][tid] + pq[3][tid];
        float mean = sum * (1.0f / 2048.0f);
        float var  = sqq * (1.0f / 2048.0f) - mean * mean;
        float sc = gamma[tid] * rsqrtf(var + 1e-5f);
        scale[tid] = sc;
        shift[tid] = beta[tid] - mean * sc;
    }
}

// ---------------------------------------------------------------------------
__global__ __launch_bounds__(512)
void fc2_kernel(const float* __restrict__ Z,      // (T,128)
                const float* __restrict__ scale,
                const float* __restrict__ shift,
                const float* __restrict__ fc2_w,  // (8,128)
                const float* __restrict__ fc2_b,
                float* __restrict__ out)          // (T,8)
{
    const int gid = blockIdx.x * blockDim.x + threadIdx.x;   // 0..16383
    const int o = gid & 7;
    const int t = gid >> 3;

    __shared__ float w_s[8][132];
    __shared__ float sc_s[128], sh_s[128];
    for (int i = threadIdx.x; i < 1024; i += 512) w_s[i >> 7][i & 127] = fc2_w[i];
    if (threadIdx.x < 128) {
        sc_s[threadIdx.x] = scale[threadIdx.x];
        sh_s[threadIdx.x] = shift[threadIdx.x];
    }
    __syncthreads();

    float acc = fc2_b[o];
    const float* zrow = Z + (size_t)t * 128;
    #pragma unroll 4
    for (int k = 0; k < 128; ++k) {
        float zn = fmaf(zrow[k], sc_s[k], sh_s[k]);
        zn = fmaxf(zn, 0.0f);
        acc = fmaf(zn, w_s[o][k], acc);
    }
    out[gid] = acc;
}

// ---------------------------------------------------------------------------
extern "C" void kernel_launch(void* const* d_in, const int* in_sizes, int n_in,
                              void* d_out, int out_size, void* d_ws, size_t ws_size,
                              hipStream_t stream)
{
    const float* x     = (const float*)d_in[0];   // (2048,128,1)
    const float* Wih0  = (const float*)d_in[1];   // (512,1)
    const float* Whh0  = (const float*)d_in[2];   // (512,128)
    const float* bih0  = (const float*)d_in[3];
    const float* bhh0  = (const float*)d_in[4];
    const float* Wih1  = (const float*)d_in[5];   // (512,128)
    const float* Whh1  = (const float*)d_in[6];   // (512,128)
    const float* bih1  = (const float*)d_in[7];
    const float* bhh1  = (const float*)d_in[8];
    const float* fc1_w = (const float*)d_in[9];   // (128,128)
    const float* fc1_b = (const float*)d_in[10];
    const float* gamma = (const float*)d_in[11];
    const float* beta  = (const float*)d_in[12];
    const float* fc2_w = (const float*)d_in[13];  // (8,128)
    const float* fc2_b = (const float*)d_in[14];
    float* out = (float*)d_out;                    // (2048,8) fp32

    float* h1    = (float*)d_ws;            // 2048*128
    float* G     = h1  + T_STEPS * HID;     // 2048*512
    float* h2    = G   + T_STEPS * G4;      // 2048*128
    float* z     = h2  + T_STEPS * HID;     // 2048*128
    float* scale = z   + T_STEPS * HID;     // 128
    float* shift = scale + 128;             // 128

    // K1: layer-0 recurrence (only batch element 127 matters)
    lstm_rec_mfma<true><<<1, 256, 0, stream>>>(Whh0, x, Wih0, bih0, bhh0, h1);

    // K2: layer-1 input GEMM: G[t,:] = h1[t,:] @ Wih1^T + (bih1+bhh1)
    dim3 g2(T_STEPS / BM, G4 / BN);
    gemm_bias_kernel<<<g2, 256, 0, stream>>>(h1, Wih1, bih1, bhh1, G, T_STEPS, G4);

    // K3: layer-1 recurrence consuming precomputed G
    lstm_rec_mfma<false><<<1, 256, 0, stream>>>(Whh1, G, nullptr, nullptr, nullptr, h2);

    // K4a: z = h2 @ fc1^T + fc1_b
    dim3 g4(T_STEPS / BM, HID / BN);
    gemm_bias_kernel<<<g4, 256, 0, stream>>>(h2, fc1_w, fc1_b, nullptr, z, T_STEPS, HID);

    // K4b: batchnorm stats over T axis
    bn_stats_kernel<<<1, 512, 0, stream>>>(z, gamma, beta, scale, shift);

    // K4c: normalize + relu + fc2
    fc2_kernel<<<T_STEPS * 8 / 512, 512, 0, stream>>>(z, scale, shift, fc2_w, fc2_b, out);
}

// Round 2
// 3378.453 us; speedup vs baseline: 1.0139x; 1.0139x over previous
//
#include <hip/hip_runtime.h>
#include <math.h>

#define T_STEPS 2048
#define HID     128
#define G4      512   // 4*H

typedef _Float16 half8 __attribute__((ext_vector_type(8)));
typedef float    f32x4 __attribute__((ext_vector_type(4)));

__device__ __forceinline__ float fast_sig(float x) {
    return __fdividef(1.0f, 1.0f + __expf(-x));
}
__device__ __forceinline__ float fast_tanh(float x) {
    return fmaf(2.0f, __fdividef(1.0f, 1.0f + __expf(-2.0f * x)), -1.0f);
}

// ---------------------------------------------------------------------------
// MFMA LSTM recurrence, single live batch element (b = 127).
//
// ROUND 6 (spill + latency-exposure fix):
//   R5 evidence: VGPR_Count=128 < demand(~220); FETCH_SIZE identical 2184 KB
//   for L0 and L1 (~1 KB/step, input-independent) = scratch spill-reload on
//   the critical path. Also 1 wave/SIMD left every VALU/LDS latency exposed.
//
//   * 8 WAVES (512 thr), wave w owns hidden units [w*16, w*16+16): all four
//     gate types, 4 row-tiles. afrag[4][4] = 64 regs/wave (was 128), pinned
//     into AGPRs via "+a" (the empirically-good VGPR=112 configuration:
//     MFMA reads A straight from AGPR, zero per-step cost). Arch-VGPR
//     demand ~58, unified ~122 < the RA's 128 budget at its 4-waves/EU
//     target (LDS held at 64000 B -> 2 WG/CU, the lever the backend
//     demonstrably respects).
//   * 2 waves/SIMD: wave A's ds_read/transcendental latency hides under
//     wave B's MFMAs. Per-SIMD MFMA issue unchanged (32/step = ~620 cy).
//   * bfrag loaded per k-tile (1-2 live half8, not 4) to stay lean.
//   * Unit-interleaved in-lane activation retained: acc[g][reg] holds gate
//     g of unit w*16 + quad*4 + reg (B is column-broadcast so all 16 cols
//     identical); lane col==cs (cs<4) gathers acc[0..3][cs] -> i/f/g/o of
//     its unit fully in-register. One barrier/step, h16 double-buffered.
// ---------------------------------------------------------------------------
template<bool IS_L0>
__global__ __launch_bounds__(512)
void lstm_rec_mfma(const float* __restrict__ Whh,   // (512,128) row-major
                   const float* __restrict__ xin,   // L0: x (T,128) ; L1: G (T,512)
                   const float* __restrict__ wih0,  // L0 only (512,)
                   const float* __restrict__ bih,   // L0 only
                   const float* __restrict__ bhh,   // L0 only
                   float* __restrict__ hout)        // (T,128)
{
    const int tid  = threadIdx.x;
    const int wave = tid >> 6;         // 0..7
    const int lane = tid & 63;
    const int quad = lane >> 4;
    const int col  = lane & 15;

    const bool act_lane = (col < 4);
    const int  u = wave * 16 + quad * 4 + col;   // hidden unit (act lanes)

    __shared__ __align__(16) _Float16 h16[2][HID];   // double-buffered h (f16)
    __shared__ float x_s[T_STEPS];                   // L0: x[t,127] table (8 KB)
    __shared__ char occupancy_pad[54 * 1024];        // total LDS = 64000 B ->
                                                     // 2 WG/CU (RA budget lever)
    ((volatile char*)occupancy_pad)[tid] = 0;        // keep the pad alive

    // afrag[g][kt] = Whh[128*g + wave*16 + col][kt*32 + quad*8 + j]
    half8 afrag[4][4];
    #pragma unroll
    for (int g = 0; g < 4; ++g) {
        const float* row = Whh + (size_t)(128 * g + wave * 16 + col) * HID;
        #pragma unroll
        for (int kt = 0; kt < 4; ++kt) {
            const float4* p = reinterpret_cast<const float4*>(row + kt * 32 + quad * 8);
            float4 lo = p[0], hi = p[1];
            half8 h;
            h[0] = (_Float16)lo.x; h[1] = (_Float16)lo.y;
            h[2] = (_Float16)lo.z; h[3] = (_Float16)lo.w;
            h[4] = (_Float16)hi.x; h[5] = (_Float16)hi.y;
            h[6] = (_Float16)hi.z; h[7] = (_Float16)hi.w;
            afrag[g][kt] = h;
        }
    }

    // L0: per-lane pre-activation constants for THIS lane's unit (8 regs)
    f32x4 bsum4 = {0,0,0,0}, w4 = {0,0,0,0};
    if (IS_L0) {
        if (act_lane) {
            #pragma unroll
            for (int g = 0; g < 4; ++g) {
                bsum4[g] = bih[128 * g + u] + bhh[128 * g + u];
                w4[g]    = wih0[128 * g + u];
            }
        }
        // x table: x[t,127,0] at stride 128
        for (int i = tid; i < T_STEPS; i += 512)
            x_s[i] = xin[(size_t)i * HID + HID - 1];
    }

    // pin weight fragments into AGPRs (MFMA reads A from AGPR directly;
    // keeps arch-VGPR demand ~58 so the RA has no reason to spill)
    #pragma unroll
    for (int g = 0; g < 4; ++g)
        #pragma unroll
        for (int kt = 0; kt < 4; ++kt) asm volatile("" : "+a"(afrag[g][kt]));
    if (IS_L0) asm volatile("" : "+v"(bsum4), "+v"(w4));

    // L1: pre-activation pipeline, 4 scalar gate values per act-lane
    f32x4 pre_cur = {0,0,0,0}, pre_nxt = {0,0,0,0};
    if (!IS_L0) {
        if (act_lane) {
            #pragma unroll
            for (int g = 0; g < 4; ++g)
                pre_cur[g] = xin[128 * g + u];     // G[0][gate]
        }
    }

    if (tid < HID) h16[0][tid] = (_Float16)0.0f;
    __syncthreads();

    float c_reg  = 0.0f;
    float h_prev = 0.0f;

    for (int t = 0; t < T_STEPS; ++t) {
        // deferred global store of h[t-1]: issued early, drained (covered)
        // at the end-of-step barrier
        if (t > 0 && act_lane)
            hout[(size_t)(t - 1) * HID + u] = h_prev;

        // L1: prefetch next step's 4 pre-activation gates
        const int tn = (t + 1 < T_STEPS) ? t + 1 : t;
        if (!IS_L0) {
            if (act_lane) {
                #pragma unroll
                for (int g = 0; g < 4; ++g)
                    pre_nxt[g] = xin[(size_t)tn * G4 + 128 * g + u];
            }
            asm volatile("" : "+v"(pre_nxt));   // force issue here
        }

        // D = Whh_tile @ h   (16 MFMA/wave, 4 independent accumulator chains)
        f32x4 acc[4] = {};
        #pragma unroll
        for (int kt = 0; kt < 4; ++kt) {
            half8 bfrag = *reinterpret_cast<const half8*>(&h16[t & 1][kt * 32 + quad * 8]);
            #pragma unroll
            for (int g = 0; g < 4; ++g)
                acc[g] = __builtin_amdgcn_mfma_f32_16x16x32_f16(
                             afrag[g][kt], bfrag, acc[g], 0, 0, 0);
        }

        // in-lane gather of this unit's i/f/g/o (static unrolled select)
        float gi = 0.f, gf = 0.f, gg = 0.f, go = 0.f;
        #pragma unroll
        for (int cs = 0; cs < 4; ++cs) {
            if (col == cs) {
                gi = acc[0][cs];
                gf = acc[1][cs];
                gg = acc[2][cs];
                go = acc[3][cs];
            }
        }

        // add pre-activation (bias + input-path contribution)
        f32x4 pre;
        if (IS_L0) {
            const float xv = x_s[t];
            pre = bsum4 + w4 * xv;
        } else {
            pre = pre_cur;
        }
        gi += pre[0]; gf += pre[1]; gg += pre[2]; go += pre[3];

        // activations + in-lane c/h update
        const float ai = fast_sig(gi);
        const float af = fast_sig(gf);
        const float ag = fast_tanh(gg);
        const float ao = fast_sig(go);
        c_reg = fmaf(af, c_reg, ai * ag);
        const float h = ao * fast_tanh(c_reg);

        if (act_lane)
            h16[(t + 1) & 1][u] = (_Float16)h;
        h_prev = h;
        if (!IS_L0) pre_cur = pre_nxt;

        __syncthreads();
    }
    if (act_lane)
        hout[(size_t)(T_STEPS - 1) * HID + u] = h_prev;
}

// ---------------------------------------------------------------------------
// C[m,n] = sum_k A[m,k] * W[n,k] + b1[n] (+ b2[n])    K = 128 fixed
// ---------------------------------------------------------------------------
#define BM 64
#define BN 64
__global__ __launch_bounds__(256)
void gemm_bias_kernel(const float* __restrict__ A,   // (M,128)
                      const float* __restrict__ W,   // (N,128)
                      const float* __restrict__ b1,
                      const float* __restrict__ b2,  // may be null
                      float* __restrict__ C,         // (M,N)
                      int M, int N)
{
    __shared__ float Al[128][BM + 4];
    __shared__ float Wl[128][BN + 4];
    const int tid    = threadIdx.x;
    const int m_base = blockIdx.x * BM;
    const int n_base = blockIdx.y * BN;

    {
        const int r  = tid >> 2;          // 0..63
        const int kq = (tid & 3) * 32;    // 0,32,64,96
        const float4* srcA = reinterpret_cast<const float4*>(A + (size_t)(m_base + r) * 128 + kq);
        #pragma unroll
        for (int i = 0; i < 8; ++i) {
            float4 v = srcA[i];
            int k = kq + 4 * i;
            Al[k + 0][r] = v.x; Al[k + 1][r] = v.y; Al[k + 2][r] = v.z; Al[k + 3][r] = v.w;
        }
        const float4* srcW = reinterpret_cast<const float4*>(W + (size_t)(n_base + r) * 128 + kq);
        #pragma unroll
        for (int i = 0; i < 8; ++i) {
            float4 v = srcW[i];
            int k = kq + 4 * i;
            Wl[k + 0][r] = v.x; Wl[k + 1][r] = v.y; Wl[k + 2][r] = v.z; Wl[k + 3][r] = v.w;
        }
    }
    __syncthreads();

    const int tm = (tid & 15) * 4;
    const int tn = (tid >> 4) * 4;
    float acc[4][4] = {};
    #pragma unroll 8
    for (int k = 0; k < 128; ++k) {
        float4 av = *reinterpret_cast<const float4*>(&Al[k][tm]);
        float4 wv = *reinterpret_cast<const float4*>(&Wl[k][tn]);
        acc[0][0] = fmaf(av.x, wv.x, acc[0][0]);
        acc[0][1] = fmaf(av.x, wv.y, acc[0][1]);
        acc[0][2] = fmaf(av.x, wv.z, acc[0][2]);
        acc[0][3] = fmaf(av.x, wv.w, acc[0][3]);
        acc[1][0] = fmaf(av.y, wv.x, acc[1][0]);
        acc[1][1] = fmaf(av.y, wv.y, acc[1][1]);
        acc[1][2] = fmaf(av.y, wv.z, acc[1][2]);
        acc[1][3] = fmaf(av.y, wv.w, acc[1][3]);
        acc[2][0] = fmaf(av.z, wv.x, acc[2][0]);
        acc[2][1] = fmaf(av.z, wv.y, acc[2][1]);
        acc[2][2] = fmaf(av.z, wv.z, acc[2][2]);
        acc[2][3] = fmaf(av.z, wv.w, acc[2][3]);
        acc[3][0] = fmaf(av.w, wv.x, acc[3][0]);
        acc[3][1] = fmaf(av.w, wv.y, acc[3][1]);
        acc[3][2] = fmaf(av.w, wv.z, acc[3][2]);
        acc[3][3] = fmaf(av.w, wv.w, acc[3][3]);
    }

    float bias[4];
    #pragma unroll
    for (int i = 0; i < 4; ++i) {
        int n = n_base + tn + i;
        bias[i] = b1[n] + (b2 ? b2[n] : 0.0f);
    }
    #pragma unroll
    for (int mi = 0; mi < 4; ++mi) {
        float4 o;
        o.x = acc[mi][0] + bias[0];
        o.y = acc[mi][1] + bias[1];
        o.z = acc[mi][2] + bias[2];
        o.w = acc[mi][3] + bias[3];
        *reinterpret_cast<float4*>(C + (size_t)(m_base + tm + mi) * N + n_base + tn) = o;
    }
}

// ---------------------------------------------------------------------------
__global__ __launch_bounds__(512)
void bn_stats_kernel(const float* __restrict__ Z,       // (T,128)
                     const float* __restrict__ gamma,
                     const float* __restrict__ beta,
                     float* __restrict__ scale,
                     float* __restrict__ shift)
{
    const int tid = threadIdx.x;
    const int col = tid & 127;
    const int seg = tid >> 7;     // 0..3
    float s = 0.f, sq = 0.f;
    for (int t = seg * 512; t < (seg + 1) * 512; ++t) {
        float v = Z[(size_t)t * 128 + col];
        s += v;
        sq = fmaf(v, v, sq);
    }
    __shared__ float ps[4][128], pq[4][128];
    ps[seg][col] = s;
    pq[seg][col] = sq;
    __syncthreads();
    if (tid < 128) {
        float sum = ps[0][tid] + ps[1][tid] + ps[2][tid] + ps[3][tid];
        float sqq = pq[0][tid] + pq[1][tid] + pq[2][tid] + pq[3][tid];
        float mean = sum * (1.0f / 2048.0f);
        float var  = sqq * (1.0f / 2048.0f) - mean * mean;
        float sc = gamma[tid] * rsqrtf(var + 1e-5f);
        scale[tid] = sc;
        shift[tid] = beta[tid] - mean * sc;
    }
}

// ---------------------------------------------------------------------------
__global__ __launch_bounds__(512)
void fc2_kernel(const float* __restrict__ Z,      // (T,128)
                const float* __restrict__ scale,
                const float* __restrict__ shift,
                const float* __restrict__ fc2_w,  // (8,128)
                const float* __restrict__ fc2_b,
                float* __restrict__ out)          // (T,8)
{
    const int gid = blockIdx.x * blockDim.x + threadIdx.x;   // 0..16383
    const int o = gid & 7;
    const int t = gid >> 3;

    __shared__ float w_s[8][132];
    __shared__ float sc_s[128], sh_s[128];
    for (int i = threadIdx.x; i < 1024; i += 512) w_s[i >> 7][i & 127] = fc2_w[i];
    if (threadIdx.x < 128) {
        sc_s[threadIdx.x] = scale[threadIdx.x];
        sh_s[threadIdx.x] = shift[threadIdx.x];
    }
    __syncthreads();

    float acc = fc2_b[o];
    const float* zrow = Z + (size_t)t * 128;
    #pragma unroll 4
    for (int k = 0; k < 128; ++k) {
        float zn = fmaf(zrow[k], sc_s[k], sh_s[k]);
        zn = fmaxf(zn, 0.0f);
        acc = fmaf(zn, w_s[o][k], acc);
    }
    out[gid] = acc;
}

// ---------------------------------------------------------------------------
extern "C" void kernel_launch(void* const* d_in, const int* in_sizes, int n_in,
                              void* d_out, int out_size, void* d_ws, size_t ws_size,
                              hipStream_t stream)
{
    const float* x     = (const float*)d_in[0];   // (2048,128,1)
    const float* Wih0  = (const float*)d_in[1];   // (512,1)
    const float* Whh0  = (const float*)d_in[2];   // (512,128)
    const float* bih0  = (const float*)d_in[3];
    const float* bhh0  = (const float*)d_in[4];
    const float* Wih1  = (const float*)d_in[5];   // (512,128)
    const float* Whh1  = (const float*)d_in[6];   // (512,128)
    const float* bih1  = (const float*)d_in[7];
    const float* bhh1  = (const float*)d_in[8];
    const float* fc1_w = (const float*)d_in[9];   // (128,128)
    const float* fc1_b = (const float*)d_in[10];
    const float* gamma = (const float*)d_in[11];
    const float* beta  = (const float*)d_in[12];
    const float* fc2_w = (const float*)d_in[13];  // (8,128)
    const float* fc2_b = (const float*)d_in[14];
    float* out = (float*)d_out;                    // (2048,8) fp32

    float* h1    = (float*)d_ws;            // 2048*128
    float* G     = h1  + T_STEPS * HID;     // 2048*512
    float* h2    = G   + T_STEPS * G4;      // 2048*128
    float* z     = h2  + T_STEPS * HID;     // 2048*128
    float* scale = z   + T_STEPS * HID;     // 128
    float* shift = scale + 128;             // 128

    // K1: layer-0 recurrence (only batch element 127 matters)
    lstm_rec_mfma<true><<<1, 512, 0, stream>>>(Whh0, x, Wih0, bih0, bhh0, h1);

    // K2: layer-1 input GEMM: G[t,:] = h1[t,:] @ Wih1^T + (bih1+bhh1)
    dim3 g2(T_STEPS / BM, G4 / BN);
    gemm_bias_kernel<<<g2, 256, 0, stream>>>(h1, Wih1, bih1, bhh1, G, T_STEPS, G4);

    // K3: layer-1 recurrence consuming precomputed G
    lstm_rec_mfma<false><<<1, 512, 0, stream>>>(Whh1, G, nullptr, nullptr, nullptr, h2);

    // K4a: z = h2 @ fc1^T + fc1_b
    dim3 g4(T_STEPS / BM, HID / BN);
    gemm_bias_kernel<<<g4, 256, 0, stream>>>(h2, fc1_w, fc1_b, nullptr, z, T_STEPS, HID);

    // K4b: batchnorm stats over T axis
    bn_stats_kernel<<<1, 512, 0, stream>>>(z, gamma, beta, scale, shift);

    // K4c: normalize + relu + fc2
    fc2_kernel<<<T_STEPS * 8 / 512, 512, 0, stream>>>(z, scale, shift, fc2_w, fc2_b, out);
}